// Round 6
// baseline (60.268 us; speedup 1.0000x reference)
//
#include <hip/hip_runtime.h>

// TreeGCN fused kernels for MI355X (gfx950) — R5.
// B=64, NODES=512, DEG=8, IN_F=64, OUT_F=64, SUP=640.
// WsF = Ws1@Ws2 precomputed (no nonlinearity between).
// R5: GEMM1 computed TRANSPOSED (S^T = Br^T x X) so the branch matrix is
// consumed directly from global as A-frags (64 independent scalar loads,
// issued up-front, no LDS on the load path). S^T keeps batch on l15 across
// the GEMM1->GEMM2 handoff, so the Ts shuffle is vectorized (b64/b128).
// 4 independent waves per 256t block, launch_bounds(256,4) -> 16 waves/CU.

typedef float f32x4 __attribute__((ext_vector_type(4)));
typedef __bf16 bf16x8 __attribute__((ext_vector_type(8)));

__device__ __forceinline__ unsigned short f2bf(float f) {
    union { float f; unsigned int u; } x; x.f = f;
    unsigned int r = x.u + 0x7FFFu + ((x.u >> 16) & 1u);
    return (unsigned short)(r >> 16);
}

#define LDP 72  // bf16 row stride (144 B)

// ---------------- prep: ylg frags + xbf frags + wsF frags + w3f frags --------
// grid 3137 x 256: [0,1024) ylg; [1024,3072) xbf; [3072,3136) wsF; 3136 w3f
__global__ __launch_bounds__(256) void tree_prep(
    const float* __restrict__ x0, const float* __restrict__ W0,
    const float* __restrict__ x1, const float* __restrict__ W1,
    const float* __restrict__ x2, const float* __restrict__ W2,
    const float* __restrict__ x3, const float* __restrict__ W3,
    const float* __restrict__ Ws1, const float* __restrict__ Ws2,
    float* __restrict__ ylg, unsigned short* __restrict__ xbf,
    unsigned short* __restrict__ wsF, unsigned short* __restrict__ w3f)
{
    const int t = threadIdx.x;
    const int blk = blockIdx.x;
    if (blk < 1024) {
        const int b = blk >> 4;
        const int g = ((blk & 15) << 2) + (t >> 6);
        const int f = t & 63;
        const float* xp = x0 + b * 96;
        float a0 = 0.f, a1 = 0.f;
        #pragma unroll 8
        for (int k = 0; k < 96; k += 2) {
            a0 += xp[k]     * W0[k * 64 + f];
            a1 += xp[k + 1] * W0[(k + 1) * 64 + f];
        }
        const float* x1p = x1 + b * 512 + (g >> 3) * 64;
        #pragma unroll 8
        for (int k = 0; k < 64; k += 2) {
            a0 += x1p[k]     * W1[k * 64 + f];
            a1 += x1p[k + 1] * W1[(k + 1) * 64 + f];
        }
        const float* x2p = x2 + b * 4096 + g * 64;
        #pragma unroll 8
        for (int k = 0; k < 64; k += 2) {
            a0 += x2p[k]     * W2[k * 64 + f];
            a1 += x2p[k + 1] * W2[(k + 1) * 64 + f];
        }
        const int mt = b >> 4, l4 = (b >> 2) & 3, r = b & 3;
        const int ft = f >> 4, l15 = f & 15;
        ylg[(size_t)((g * 4 + mt) * 4 + ft) * 256 + (l4 * 16 + l15) * 4 + r] = a0 + a1;
    } else if (blk < 3072) {
        const int bb = blk - 1024;
        const int b = bb >> 5, ngrp = bb & 31;
        const int n = ngrp * 16 + (t >> 4), k0 = 4 * (t & 15);
        float4 v = *(const float4*)(x3 + (size_t)b * 32768 + (size_t)n * 64 + k0);
        const int mt = b >> 4, l15b = b & 15, ks = k0 >> 5, l4k = (k0 >> 3) & 3, j = k0 & 7;
        union { unsigned short h[4]; uint2 u; } p;
        p.h[0] = f2bf(v.x); p.h[1] = f2bf(v.y); p.h[2] = f2bf(v.z); p.h[3] = f2bf(v.w);
        *(uint2*)&xbf[(size_t)n * 4096 + ((mt * 2 + ks) * 64 + l4k * 16 + l15b) * 8 + j] = p.u;
    } else if (blk < 3136) {
        __shared__ float red[4][64];
        const int c = blk - 3072;
        const int f = t & 63, q = t >> 6;
        const float* w1p = Ws1 + (size_t)c * 640 + q * 160;
        const float* w2p = Ws2 + (size_t)(q * 160) * 64 + f;
        float a0 = 0.f, a1 = 0.f;
        #pragma unroll 8
        for (int s = 0; s < 160; s += 2) {
            a0 += w1p[s]     * w2p[(size_t)s * 64];
            a1 += w1p[s + 1] * w2p[(size_t)(s + 1) * 64];
        }
        red[q][f] = a0 + a1;
        __syncthreads();
        if (q == 0) {
            const float v = red[0][f] + red[1][f] + red[2][f] + red[3][f];
            const int ks = c >> 5, l4c = (c >> 3) & 3, j = c & 7;
            wsF[((f >> 4) * 2 + ks) * 512 + (l4c * 16 + (f & 15)) * 8 + j] = f2bf(v);
        }
    } else {
        const int l = t & 63;
        #pragma unroll
        for (int it = 0; it < 2; ++it) {
            const int fh = it * 4 + (t >> 6);
            const int ft = fh >> 1, ks = fh & 1;
            const int f = ft * 16 + (l & 15);
            const int kb = ks * 32 + (l >> 4) * 8;
            union { unsigned short h[8]; uint4 u; } p;
            #pragma unroll
            for (int j = 0; j < 8; ++j) p.h[j] = f2bf(W3[(kb + j) * 64 + f]);
            *(uint4*)&w3f[((size_t)fh * 64 + l) * 8] = p.u;
        }
    }
}

// ---------------- main: 4 independent waves per block, wave = (n, d) ---------
// grid 1024 x 256: id = blk*4 + wave; n = id>>3, d = id&7
__global__ __launch_bounds__(256, 4) void tree_main(
    const float* __restrict__ branch, const float* __restrict__ bias,
    const float* __restrict__ ylg, const unsigned short* __restrict__ xbf,
    const unsigned short* __restrict__ wsF, const unsigned short* __restrict__ w3f,
    float* __restrict__ out)
{
    __shared__ unsigned short Ts[4][64 * LDP];  // per-wave T [b][c] bf16
    const int t = threadIdx.x;
    const int w = t >> 6, l = t & 63;
    const int l15 = l & 15, l4 = l >> 4;
    const int id = blockIdx.x * 4 + w;
    const int n = id >> 3, d = id & 7;
    const int g = n >> 3;
    unsigned short* ts = Ts[w];

    // ---- raw branch loads: A-operand of S^T, straight from global.
    // instr (cP,ks,j): lanes read 4x64B segments — all 64 loads independent.
    const float* brp = branch + (size_t)n * 32768 + d * 64;
    float raw[4][2][8];
    #pragma unroll
    for (int cP = 0; cP < 4; ++cP)
        #pragma unroll
        for (int ks = 0; ks < 2; ++ks)
            #pragma unroll
            for (int j = 0; j < 8; ++j)
                raw[cP][ks][j] = brp[(size_t)(32 * ks + 8 * l4 + j) * 512 + 16 * cP + l15];

    // ---- X frags (coalesced dwordx4; L2-shared by the 8 d-waves of n)
    bf16x8 bx[4][2];
    #pragma unroll
    for (int bt = 0; bt < 4; ++bt)
        #pragma unroll
        for (int ks = 0; ks < 2; ++ks)
            bx[bt][ks] = *(const bf16x8*)(xbf + (size_t)n * 4096 +
                                          ((bt * 2 + ks) * 64 + l) * 8);

    // ---- cvt raw -> Br^T frags (frees raw)
    bf16x8 pf[4][2];
    #pragma unroll
    for (int cP = 0; cP < 4; ++cP)
        #pragma unroll
        for (int ks = 0; ks < 2; ++ks) {
            union { unsigned short h[8]; bf16x8 bv; } p;
            #pragma unroll
            for (int j = 0; j < 8; ++j) p.h[j] = f2bf(raw[cP][ks][j]);
            pf[cP][ks] = p.bv;
        }

    // ---- GEMM1^T: S^T[c][b] = sum_k Br[k,c] * X[b,k]
    f32x4 st[4][4];  // [cP][bt]
    #pragma unroll
    for (int cP = 0; cP < 4; ++cP)
        #pragma unroll
        for (int bt = 0; bt < 4; ++bt) {
            f32x4 acc = {0.f, 0.f, 0.f, 0.f};
            acc = __builtin_amdgcn_mfma_f32_16x16x32_bf16(pf[cP][0], bx[bt][0], acc, 0, 0, 0);
            acc = __builtin_amdgcn_mfma_f32_16x16x32_bf16(pf[cP][1], bx[bt][1], acc, 0, 0, 0);
            st[cP][bt] = acc;
        }

    // ---- lrelu -> bf16 -> Ts (vectorized b64 writes: c is contiguous)
    #pragma unroll
    for (int bt = 0; bt < 4; ++bt)
        #pragma unroll
        for (int cP = 0; cP < 4; ++cP) {
            union { unsigned short h[4]; uint2 u; } q;
            #pragma unroll
            for (int r = 0; r < 4; ++r) {
                float v = st[cP][bt][r];
                v = fmaxf(v, 0.2f * v);
                q.h[r] = f2bf(v);
            }
            *(uint2*)&ts[(16 * bt + l15) * LDP + 16 * cP + 4 * l4] = q.u;
        }

    // ---- phase-2 weights (tiny, L1/L2-hot)
    bf16x8 w3[4][2], wf[4][2];
    #pragma unroll
    for (int ft = 0; ft < 4; ++ft)
        #pragma unroll
        for (int ks = 0; ks < 2; ++ks) {
            w3[ft][ks] = *(const bf16x8*)(w3f + (size_t)((ft * 2 + ks) * 64 + l) * 8);
            wf[ft][ks] = *(const bf16x8*)(wsF + (size_t)((ft * 2 + ks) * 64 + l) * 8);
        }
    float bv[4];
    #pragma unroll
    for (int ft = 0; ft < 4; ++ft) bv[ft] = bias[d * 64 + 16 * ft + l15];

    // ---- per-bt: y = ylg + X@W3 + T@WsF ; epilogue
    float* outp = out + (size_t)(n * 8 + d) * 64;
    #pragma unroll
    for (int bt = 0; bt < 4; ++bt) {
        f32x4 y[4];
        #pragma unroll
        for (int ft = 0; ft < 4; ++ft)
            y[ft] = *(const f32x4*)(ylg + (size_t)((g * 4 + bt) * 4 + ft) * 256 + l * 4);
        bf16x8 a20 = *(const bf16x8*)&ts[(16 * bt + l15) * LDP + 8 * l4];
        bf16x8 a21 = *(const bf16x8*)&ts[(16 * bt + l15) * LDP + 32 + 8 * l4];
        #pragma unroll
        for (int ft = 0; ft < 4; ++ft) {
            y[ft] = __builtin_amdgcn_mfma_f32_16x16x32_bf16(bx[bt][0], w3[ft][0], y[ft], 0, 0, 0);
            y[ft] = __builtin_amdgcn_mfma_f32_16x16x32_bf16(bx[bt][1], w3[ft][1], y[ft], 0, 0, 0);
            y[ft] = __builtin_amdgcn_mfma_f32_16x16x32_bf16(a20, wf[ft][0], y[ft], 0, 0, 0);
            y[ft] = __builtin_amdgcn_mfma_f32_16x16x32_bf16(a21, wf[ft][1], y[ft], 0, 0, 0);
        }
        #pragma unroll
        for (int ft = 0; ft < 4; ++ft)
            #pragma unroll
            for (int r = 0; r < 4; ++r) {
                float val = y[ft][r] + bv[ft];
                val = fmaxf(val, 0.2f * val);
                outp[(size_t)(16 * bt + 4 * l4 + r) * 262144 + 16 * ft + l15] = val;
            }
    }
}

extern "C" void kernel_launch(void* const* d_in, const int* in_sizes, int n_in,
                              void* d_out, int out_size, void* d_ws, size_t ws_size,
                              hipStream_t stream) {
    (void)in_sizes; (void)n_in; (void)out_size; (void)ws_size;
    const float* x0     = (const float*)d_in[0];
    const float* W0     = (const float*)d_in[1];
    const float* x1     = (const float*)d_in[2];
    const float* W1     = (const float*)d_in[3];
    const float* x2     = (const float*)d_in[4];
    const float* W2     = (const float*)d_in[5];
    const float* x3     = (const float*)d_in[6];
    const float* W3     = (const float*)d_in[7];
    const float* branch = (const float*)d_in[8];
    const float* Ws1    = (const float*)d_in[9];
    const float* Ws2    = (const float*)d_in[10];
    const float* bias   = (const float*)d_in[11];

    float* ylg          = (float*)d_ws;                                   // 1 MiB
    unsigned short* xbf = (unsigned short*)((char*)d_ws + 1048576);       // 4 MiB
    unsigned short* wsF = (unsigned short*)((char*)d_ws + 5242880);       // 8 KiB
    unsigned short* w3f = (unsigned short*)((char*)d_ws + 5251072);       // 8 KiB
    float* out = (float*)d_out;

    tree_prep<<<3137, 256, 0, stream>>>(x0, W0, x1, W1, x2, W2, x3, W3, Ws1, Ws2,
                                        ylg, xbf, wsF, w3f);
    tree_main<<<1024, 256, 0, stream>>>(branch, bias, ylg, xbf, wsF, w3f, out);
}

// Round 7
// 52.023 us; speedup vs baseline: 1.1585x; 1.1585x over previous
//
#include <hip/hip_runtime.h>

// TreeGCN fused kernels for MI355X (gfx950) — R6.
// B=64, NODES=512, DEG=8, IN_F=64, OUT_F=64, SUP=640.
// WsF = Ws1@Ws2 precomputed (no nonlinearity between).
// R6 = R5 de-spilled: transposed GEMM1 (S^T = Br^T x X, branch consumed
// directly from global as A-frags, all 64 scalar loads issued up-front),
// but GEMM1 accumulators are scoped PER-cP (16 regs transient) with Ts
// writes inside the cP loop. launch_bounds(256,3) -> no spill, 12 waves/CU,
// ~20KB of independent loads in flight per wave, zero barriers.

typedef float f32x4 __attribute__((ext_vector_type(4)));
typedef __bf16 bf16x8 __attribute__((ext_vector_type(8)));

__device__ __forceinline__ unsigned short f2bf(float f) {
    union { float f; unsigned int u; } x; x.f = f;
    unsigned int r = x.u + 0x7FFFu + ((x.u >> 16) & 1u);
    return (unsigned short)(r >> 16);
}

#define LDP 72  // bf16 row stride (144 B)

// ---------------- prep: ylg frags + xbf frags + wsF frags + w3f frags --------
// grid 3137 x 256: [0,1024) ylg; [1024,3072) xbf; [3072,3136) wsF; 3136 w3f
__global__ __launch_bounds__(256) void tree_prep(
    const float* __restrict__ x0, const float* __restrict__ W0,
    const float* __restrict__ x1, const float* __restrict__ W1,
    const float* __restrict__ x2, const float* __restrict__ W2,
    const float* __restrict__ x3, const float* __restrict__ W3,
    const float* __restrict__ Ws1, const float* __restrict__ Ws2,
    float* __restrict__ ylg, unsigned short* __restrict__ xbf,
    unsigned short* __restrict__ wsF, unsigned short* __restrict__ w3f)
{
    const int t = threadIdx.x;
    const int blk = blockIdx.x;
    if (blk < 1024) {
        const int b = blk >> 4;
        const int g = ((blk & 15) << 2) + (t >> 6);
        const int f = t & 63;
        const float* xp = x0 + b * 96;
        float a0 = 0.f, a1 = 0.f;
        #pragma unroll 8
        for (int k = 0; k < 96; k += 2) {
            a0 += xp[k]     * W0[k * 64 + f];
            a1 += xp[k + 1] * W0[(k + 1) * 64 + f];
        }
        const float* x1p = x1 + b * 512 + (g >> 3) * 64;
        #pragma unroll 8
        for (int k = 0; k < 64; k += 2) {
            a0 += x1p[k]     * W1[k * 64 + f];
            a1 += x1p[k + 1] * W1[(k + 1) * 64 + f];
        }
        const float* x2p = x2 + b * 4096 + g * 64;
        #pragma unroll 8
        for (int k = 0; k < 64; k += 2) {
            a0 += x2p[k]     * W2[k * 64 + f];
            a1 += x2p[k + 1] * W2[(k + 1) * 64 + f];
        }
        const int mt = b >> 4, l4 = (b >> 2) & 3, r = b & 3;
        const int ft = f >> 4, l15 = f & 15;
        ylg[(size_t)((g * 4 + mt) * 4 + ft) * 256 + (l4 * 16 + l15) * 4 + r] = a0 + a1;
    } else if (blk < 3072) {
        const int bb = blk - 1024;
        const int b = bb >> 5, ngrp = bb & 31;
        const int n = ngrp * 16 + (t >> 4), k0 = 4 * (t & 15);
        float4 v = *(const float4*)(x3 + (size_t)b * 32768 + (size_t)n * 64 + k0);
        const int mt = b >> 4, l15b = b & 15, ks = k0 >> 5, l4k = (k0 >> 3) & 3, j = k0 & 7;
        union { unsigned short h[4]; uint2 u; } p;
        p.h[0] = f2bf(v.x); p.h[1] = f2bf(v.y); p.h[2] = f2bf(v.z); p.h[3] = f2bf(v.w);
        *(uint2*)&xbf[(size_t)n * 4096 + ((mt * 2 + ks) * 64 + l4k * 16 + l15b) * 8 + j] = p.u;
    } else if (blk < 3136) {
        __shared__ float red[4][64];
        const int c = blk - 3072;
        const int f = t & 63, q = t >> 6;
        const float* w1p = Ws1 + (size_t)c * 640 + q * 160;
        const float* w2p = Ws2 + (size_t)(q * 160) * 64 + f;
        float a0 = 0.f, a1 = 0.f;
        #pragma unroll 8
        for (int s = 0; s < 160; s += 2) {
            a0 += w1p[s]     * w2p[(size_t)s * 64];
            a1 += w1p[s + 1] * w2p[(size_t)(s + 1) * 64];
        }
        red[q][f] = a0 + a1;
        __syncthreads();
        if (q == 0) {
            const float v = red[0][f] + red[1][f] + red[2][f] + red[3][f];
            const int ks = c >> 5, l4c = (c >> 3) & 3, j = c & 7;
            wsF[((f >> 4) * 2 + ks) * 512 + (l4c * 16 + (f & 15)) * 8 + j] = f2bf(v);
        }
    } else {
        const int l = t & 63;
        #pragma unroll
        for (int it = 0; it < 2; ++it) {
            const int fh = it * 4 + (t >> 6);
            const int ft = fh >> 1, ks = fh & 1;
            const int f = ft * 16 + (l & 15);
            const int kb = ks * 32 + (l >> 4) * 8;
            union { unsigned short h[8]; uint4 u; } p;
            #pragma unroll
            for (int j = 0; j < 8; ++j) p.h[j] = f2bf(W3[(kb + j) * 64 + f]);
            *(uint4*)&w3f[((size_t)fh * 64 + l) * 8] = p.u;
        }
    }
}

// ---------------- main: 4 independent waves per block, wave = (n, d) ---------
// grid 1024 x 256: id = blk*4 + wave; n = id>>3, d = id&7
__global__ __launch_bounds__(256, 3) void tree_main(
    const float* __restrict__ branch, const float* __restrict__ bias,
    const float* __restrict__ ylg, const unsigned short* __restrict__ xbf,
    const unsigned short* __restrict__ wsF, const unsigned short* __restrict__ w3f,
    float* __restrict__ out)
{
    __shared__ unsigned short Ts[4][64 * LDP];  // per-wave T [b][c] bf16
    const int t = threadIdx.x;
    const int w = t >> 6, l = t & 63;
    const int l15 = l & 15, l4 = l >> 4;
    const int id = blockIdx.x * 4 + w;
    const int n = id >> 3, d = id & 7;
    const int g = n >> 3;
    unsigned short* ts = Ts[w];

    // ---- raw branch loads: A-operand of S^T, straight from global.
    // instr (cP,ks,j): lanes read 4x64B segments — all 64 loads independent,
    // issued before anything else (deep per-wave stream).
    const float* brp = branch + (size_t)n * 32768 + d * 64;
    float raw[4][2][8];
    #pragma unroll
    for (int cP = 0; cP < 4; ++cP)
        #pragma unroll
        for (int ks = 0; ks < 2; ++ks)
            #pragma unroll
            for (int j = 0; j < 8; ++j)
                raw[cP][ks][j] = brp[(size_t)(32 * ks + 8 * l4 + j) * 512 + 16 * cP + l15];

    // ---- X frags (coalesced dwordx4; L2-shared by the 8 d-waves of n)
    bf16x8 bx[4][2];
    #pragma unroll
    for (int bt = 0; bt < 4; ++bt)
        #pragma unroll
        for (int ks = 0; ks < 2; ++ks)
            bx[bt][ks] = *(const bf16x8*)(xbf + (size_t)n * 4096 +
                                          ((bt * 2 + ks) * 64 + l) * 8);

    // ---- GEMM1^T streamed per cP: cvt (frees raw[cP]) -> 8 MFMA -> Ts write.
    // Accumulators live only within one cP iteration (16 VGPR transient).
    #pragma unroll
    for (int cP = 0; cP < 4; ++cP) {
        bf16x8 pf0, pf1;
        {
            union { unsigned short h[8]; bf16x8 bv; } p0, p1;
            #pragma unroll
            for (int j = 0; j < 8; ++j) {
                p0.h[j] = f2bf(raw[cP][0][j]);
                p1.h[j] = f2bf(raw[cP][1][j]);
            }
            pf0 = p0.bv; pf1 = p1.bv;
        }
        #pragma unroll
        for (int bt = 0; bt < 4; ++bt) {
            f32x4 acc = {0.f, 0.f, 0.f, 0.f};
            acc = __builtin_amdgcn_mfma_f32_16x16x32_bf16(pf0, bx[bt][0], acc, 0, 0, 0);
            acc = __builtin_amdgcn_mfma_f32_16x16x32_bf16(pf1, bx[bt][1], acc, 0, 0, 0);
            // st^T[c][b]: row c = 16cP+4l4+r, col b = 16bt+l15
            union { unsigned short h[4]; uint2 u; } q;
            #pragma unroll
            for (int r = 0; r < 4; ++r) {
                float v = acc[r];
                v = fmaxf(v, 0.2f * v);
                q.h[r] = f2bf(v);
            }
            *(uint2*)&ts[(16 * bt + l15) * LDP + 16 * cP + 4 * l4] = q.u;
        }
    }

    // ---- phase-2 weights (tiny, L1/L2-hot)
    bf16x8 w3[4][2], wf[4][2];
    #pragma unroll
    for (int ft = 0; ft < 4; ++ft)
        #pragma unroll
        for (int ks = 0; ks < 2; ++ks) {
            w3[ft][ks] = *(const bf16x8*)(w3f + (size_t)((ft * 2 + ks) * 64 + l) * 8);
            wf[ft][ks] = *(const bf16x8*)(wsF + (size_t)((ft * 2 + ks) * 64 + l) * 8);
        }
    float bv[4];
    #pragma unroll
    for (int ft = 0; ft < 4; ++ft) bv[ft] = bias[d * 64 + 16 * ft + l15];

    // ---- per-bt: y = ylg + X@W3 + T@WsF ; epilogue
    float* outp = out + (size_t)(n * 8 + d) * 64;
    #pragma unroll
    for (int bt = 0; bt < 4; ++bt) {
        f32x4 y[4];
        #pragma unroll
        for (int ft = 0; ft < 4; ++ft)
            y[ft] = *(const f32x4*)(ylg + (size_t)((g * 4 + bt) * 4 + ft) * 256 + l * 4);
        bf16x8 a20 = *(const bf16x8*)&ts[(16 * bt + l15) * LDP + 8 * l4];
        bf16x8 a21 = *(const bf16x8*)&ts[(16 * bt + l15) * LDP + 32 + 8 * l4];
        #pragma unroll
        for (int ft = 0; ft < 4; ++ft) {
            y[ft] = __builtin_amdgcn_mfma_f32_16x16x32_bf16(bx[bt][0], w3[ft][0], y[ft], 0, 0, 0);
            y[ft] = __builtin_amdgcn_mfma_f32_16x16x32_bf16(bx[bt][1], w3[ft][1], y[ft], 0, 0, 0);
            y[ft] = __builtin_amdgcn_mfma_f32_16x16x32_bf16(a20, wf[ft][0], y[ft], 0, 0, 0);
            y[ft] = __builtin_amdgcn_mfma_f32_16x16x32_bf16(a21, wf[ft][1], y[ft], 0, 0, 0);
        }
        #pragma unroll
        for (int ft = 0; ft < 4; ++ft)
            #pragma unroll
            for (int r = 0; r < 4; ++r) {
                float val = y[ft][r] + bv[ft];
                val = fmaxf(val, 0.2f * val);
                outp[(size_t)(16 * bt + 4 * l4 + r) * 262144 + 16 * ft + l15] = val;
            }
    }
}

extern "C" void kernel_launch(void* const* d_in, const int* in_sizes, int n_in,
                              void* d_out, int out_size, void* d_ws, size_t ws_size,
                              hipStream_t stream) {
    (void)in_sizes; (void)n_in; (void)out_size; (void)ws_size;
    const float* x0     = (const float*)d_in[0];
    const float* W0     = (const float*)d_in[1];
    const float* x1     = (const float*)d_in[2];
    const float* W1     = (const float*)d_in[3];
    const float* x2     = (const float*)d_in[4];
    const float* W2     = (const float*)d_in[5];
    const float* x3     = (const float*)d_in[6];
    const float* W3     = (const float*)d_in[7];
    const float* branch = (const float*)d_in[8];
    const float* Ws1    = (const float*)d_in[9];
    const float* Ws2    = (const float*)d_in[10];
    const float* bias   = (const float*)d_in[11];

    float* ylg          = (float*)d_ws;                                   // 1 MiB
    unsigned short* xbf = (unsigned short*)((char*)d_ws + 1048576);       // 4 MiB
    unsigned short* wsF = (unsigned short*)((char*)d_ws + 5242880);       // 8 KiB
    unsigned short* w3f = (unsigned short*)((char*)d_ws + 5251072);       // 8 KiB
    float* out = (float*)d_out;

    tree_prep<<<3137, 256, 0, stream>>>(x0, W0, x1, W1, x2, W2, x3, W3, Ws1, Ws2,
                                        ylg, xbf, wsF, w3f);
    tree_main<<<1024, 256, 0, stream>>>(branch, bias, ylg, xbf, wsF, w3f, out);
}